// Round 1
// baseline (544.975 us; speedup 1.0000x reference)
//
#include <hip/hip_runtime.h>

typedef unsigned int u32;
typedef unsigned short u16;
typedef __attribute__((ext_vector_type(8))) short bf16x8;   // 8 bf16 in 4 VGPRs
typedef __attribute__((ext_vector_type(4))) float f32x4;

#define GLOBAL_AS __attribute__((address_space(1)))
#define LDS_AS    __attribute__((address_space(3)))

#define B_   64
#define T_   256
#define E_   1024
#define H_   16
#define HD_  64
#define NTOK (B_*T_)          // 16384
#define K_   1024
#define LNEPS 1e-5f

// ---------- bf16 helpers ----------
__device__ __forceinline__ float bflo(u32 u){ return __uint_as_float(u << 16); }
__device__ __forceinline__ float bfhi(u32 u){ return __uint_as_float(u & 0xffff0000u); }
__device__ __forceinline__ u16 f2bf(float f){            // round-to-nearest-even
  u32 x = __float_as_uint(f);
  u32 r = x + 0x7fffu + ((x >> 16) & 1u);
  return (u16)(r >> 16);
}
__device__ __forceinline__ u16 f2bf_trunc(float f){      // truncate (P probs only)
  return (u16)(__float_as_uint(f) >> 16);
}
__device__ __forceinline__ u32 pack2(float a, float b){
  return (u32)f2bf(a) | ((u32)f2bf(b) << 16);
}

// async global->LDS, 16 B per lane (dest = wave-uniform base + lane*16)
__device__ __forceinline__ void gload16(const u16* g, u16* l){
  __builtin_amdgcn_global_load_lds((const GLOBAL_AS void*)g, (LDS_AS void*)l, 16, 0, 0);
}

// ---------- fused LayerNorm fp32 -> bf16, one wave per token ----------
__global__ __launch_bounds__(256) void ln_bf16_kernel(
    const float* __restrict__ x, const float* __restrict__ g,
    const float* __restrict__ b, u16* __restrict__ o)
{
  int lane  = threadIdx.x & 63;
  int token = (blockIdx.x << 2) + (threadIdx.x >> 6);
  const float4* xr = (const float4*)(x + (size_t)token * E_);
  float4 v[4];
  float s = 0.f, ss = 0.f;
  #pragma unroll
  for (int i = 0; i < 4; ++i){
    v[i] = xr[lane + 64 * i];
    s += v[i].x + v[i].y + v[i].z + v[i].w;
    ss = fmaf(v[i].x, v[i].x, fmaf(v[i].y, v[i].y,
         fmaf(v[i].z, v[i].z, fmaf(v[i].w, v[i].w, ss))));
  }
  #pragma unroll
  for (int off = 32; off > 0; off >>= 1){
    s  += __shfl_xor(s,  off);
    ss += __shfl_xor(ss, off);
  }
  float mu   = s * (1.f / E_);
  float var  = ss * (1.f / E_) - mu * mu;
  float rstd = rsqrtf(var + LNEPS);
  const float4* gr = (const float4*)g;
  const float4* br = (const float4*)b;
  uint2* orow = (uint2*)(o + (size_t)token * E_);
  #pragma unroll
  for (int i = 0; i < 4; ++i){
    float4 gg = gr[lane + 64 * i], bb = br[lane + 64 * i];
    float y0 = (v[i].x - mu) * rstd * gg.x + bb.x;
    float y1 = (v[i].y - mu) * rstd * gg.y + bb.y;
    float y2 = (v[i].z - mu) * rstd * gg.z + bb.z;
    float y3 = (v[i].w - mu) * rstd * gg.w + bb.w;
    orow[lane + 64 * i] = make_uint2(pack2(y0, y1), pack2(y2, y3));
  }
}

// ---------- weight prep (coalesced, LDS transpose) ----------
__global__ __launch_bounds__(256) void convq_kernel(
    const float* __restrict__ wk, const float* __restrict__ wq,
    const float* __restrict__ wv, u16* __restrict__ o)
{
  __shared__ float tile[64 * 68];
  const int zh = blockIdx.x, z = zh >> 4, h = zh & 15;
  const int e0 = blockIdx.y << 6;
  const float* w = (z == 0 ? wk : z == 1 ? wq : wv) + (size_t)h * (E_ * HD_);
  const int t = threadIdx.x;
  {
    int er = t >> 2, d0 = (t & 3) << 4;
    const float4* src = (const float4*)(w + (size_t)(e0 + er) * HD_ + d0);
    #pragma unroll
    for (int i = 0; i < 4; ++i)
      *(float4*)(tile + er * 68 + d0 + 4 * i) = src[i];
  }
  __syncthreads();
  {
    int dr = t >> 2, ee = (t & 3) << 4;
    u32 wd[8];
    #pragma unroll
    for (int j = 0; j < 8; ++j)
      wd[j] = pack2(tile[(ee + 2*j) * 68 + dr], tile[(ee + 2*j + 1) * 68 + dr]);
    u16* dst = o + (size_t)(z * 1024 + h * 64 + dr) * K_ + e0 + ee;
    *(uint4*)(dst    ) = make_uint4(wd[0], wd[1], wd[2], wd[3]);
    *(uint4*)(dst + 8) = make_uint4(wd[4], wd[5], wd[6], wd[7]);
  }
}

__global__ __launch_bounds__(256) void convt_kernel(
    const float* __restrict__ w, u16* __restrict__ o)
{
  __shared__ float tile[64 * 68];
  const int n0 = blockIdx.x << 6, k0 = blockIdx.y << 6;
  const int t = threadIdx.x;
  {
    int kr = t >> 2, nn = (t & 3) << 4;
    const float4* src = (const float4*)(w + (size_t)(k0 + kr) * E_ + n0 + nn);
    #pragma unroll
    for (int i = 0; i < 4; ++i)
      *(float4*)(tile + kr * 68 + nn + 4 * i) = src[i];
  }
  __syncthreads();
  {
    int nr = t >> 2, kk = (t & 3) << 4;
    u32 wd[8];
    #pragma unroll
    for (int j = 0; j < 8; ++j)
      wd[j] = pack2(tile[(kk + 2*j) * 68 + nr], tile[(kk + 2*j + 1) * 68 + nr]);
    u16* dst = o + (size_t)(n0 + nr) * K_ + k0 + kk;
    *(uint4*)(dst    ) = make_uint4(wd[0], wd[1], wd[2], wd[3]);
    *(uint4*)(dst + 8) = make_uint4(wd[4], wd[5], wd[6], wd[7]);
  }
}

// ---------- MFMA GEMM: C(M x N) = A(M x 1024) * Bt(N x 1024)^T ----------
// 256x256 tile / 512 threads (8 waves, 2M x 4N), 8-phase counted-vmcnt pipeline.
// LDS = 4-slot ring (BK=32): slot = A[256x32] + B[256x32] bf16 = 32 KiB, 128 KiB total.
// Rows are 4 chunks of 16 B, XOR-swizzled: phys = log ^ ((r + r/4) & 3) (<=2-way banks).
// global_load_lds dest stays lane-LINEAR; the swizzle is applied on the per-lane
// GLOBAL source address (both-sides-or-neither rule).
// Pipeline: 3 slices (12 loads/thread-group) in flight. Per slice, 2 phases of
// {ds_read_b128 subtile || 2 gload16 -> s_barrier -> lgkmcnt(0) -> 16 MFMA}, and
// one s_waitcnt vmcnt(8) per slice before its end barrier -- NEVER vmcnt(0) in
// the main loop.  Epilogue modes as before:
// MODE 0: qkv -> k,q bf16 (b,h,t,d); v bf16 TRANSPOSED (b,h,d,t)
// MODE 1: proj -> Cf fp32 = acc + bias + resid              [row-major]
// MODE 2: ff1  -> Cb bf16 = relu(acc + bias)
// MODE 3: ff2  -> Cf fp32 = acc + bias + Cf (in-place residual)
#define MF4(I, AV)                                                                 \
  acc[I][0] = __builtin_amdgcn_mfma_f32_16x16x32_bf16(AV, b0, acc[I][0], 0, 0, 0); \
  acc[I][1] = __builtin_amdgcn_mfma_f32_16x16x32_bf16(AV, b1, acc[I][1], 0, 0, 0); \
  acc[I][2] = __builtin_amdgcn_mfma_f32_16x16x32_bf16(AV, b2, acc[I][2], 0, 0, 0); \
  acc[I][3] = __builtin_amdgcn_mfma_f32_16x16x32_bf16(AV, b3, acc[I][3], 0, 0, 0);

#define MG_SLICE(SLOT, DSTSLOT, KOFF, DO_STAGE, VM)                           \
  {                                                                           \
    const u16* As_ = lds + (SLOT) * 16384;                                    \
    const u16* Bs_ = As_ + 8192;                                              \
    u16* dst_ = lds + (DSTSLOT) * 16384;                                      \
    bf16x8 b0 = *(const bf16x8*)(Bs_ + boff);                                 \
    bf16x8 b1 = *(const bf16x8*)(Bs_ + boff + 512);                           \
    bf16x8 b2 = *(const bf16x8*)(Bs_ + boff + 1024);                          \
    bf16x8 b3 = *(const bf16x8*)(Bs_ + boff + 1536);                          \
    bf16x8 a0 = *(const bf16x8*)(As_ + aoff);                                 \
    bf16x8 a1 = *(const bf16x8*)(As_ + aoff + 512);                           \
    bf16x8 a2 = *(const bf16x8*)(As_ + aoff + 1024);                          \
    bf16x8 a3 = *(const bf16x8*)(As_ + aoff + 1536);                          \
    if (DO_STAGE) {                                                           \
      gload16(Ag0 + (KOFF), dst_ + tid * 8);                                  \
      gload16(Ag1 + (KOFF), dst_ + 4096 + tid * 8);                           \
    }                                                                         \
    __builtin_amdgcn_s_barrier();                                             \
    asm volatile("s_waitcnt lgkmcnt(0)" ::: "memory");                        \
    __builtin_amdgcn_sched_barrier(0);                                        \
    __builtin_amdgcn_s_setprio(1);                                            \
    MF4(0, a0) MF4(1, a1) MF4(2, a2) MF4(3, a3)                               \
    __builtin_amdgcn_s_setprio(0);                                            \
    __builtin_amdgcn_s_barrier();                                             \
    asm volatile("" ::: "memory");                                            \
    a0 = *(const bf16x8*)(As_ + aoff + 2048);                                 \
    a1 = *(const bf16x8*)(As_ + aoff + 2560);                                 \
    a2 = *(const bf16x8*)(As_ + aoff + 3072);                                 \
    a3 = *(const bf16x8*)(As_ + aoff + 3584);                                 \
    if (DO_STAGE) {                                                           \
      gload16(Bg0 + (KOFF), dst_ + 8192 + tid * 8);                           \
      gload16(Bg1 + (KOFF), dst_ + 12288 + tid * 8);                          \
    }                                                                         \
    __builtin_amdgcn_s_barrier();                                             \
    asm volatile("s_waitcnt lgkmcnt(0)" ::: "memory");                        \
    __builtin_amdgcn_sched_barrier(0);                                        \
    __builtin_amdgcn_s_setprio(1);                                            \
    MF4(4, a0) MF4(5, a1) MF4(6, a2) MF4(7, a3)                               \
    __builtin_amdgcn_s_setprio(0);                                            \
    VM;                                                                       \
    __builtin_amdgcn_s_barrier();                                             \
    asm volatile("" ::: "memory");                                            \
  }

template<int MODE>
__global__ __launch_bounds__(512, 2) void mgemm_kernel(
    const u16* __restrict__ A, const u16* __restrict__ Bt,
    const float* __restrict__ bias, const float* __restrict__ resid,
    float* __restrict__ Cf, u16* __restrict__ Cb, u16* __restrict__ Cb2)
{
  __shared__ __align__(16) u16 lds[65536];   // 128 KiB ring, reused by epilogue

  const int tid = threadIdx.x, lane = tid & 63, wid = tid >> 6;
  const int wm = wid >> 2, wn = wid & 3;
  const int l15 = lane & 15, quad = lane >> 4;

  // XCD-aware tile swizzle (nwg % 8 == 0 for all launches; gridDim.x == 64)
  const int nwg = (int)(gridDim.x * gridDim.y);
  int wg = (int)(blockIdx.y * gridDim.x + blockIdx.x);
  wg = (wg & 7) * (nwg >> 3) + (wg >> 3);
  const int row0 = (wg & 63) << 8;
  const int col0 = (wg >> 6) << 8;

  // staging: thread covers 16B chunk (tid&3) of local rows (tid>>2) and (tid>>2)+128.
  // swz(r) = (r + r/4) & 3 is identical for r and r+128.
  const int srow = tid >> 2;
  const int slog = (tid & 3) ^ ((srow + (srow >> 2)) & 3);
  const u16* Ag0 = A  + (size_t)(row0 + srow) * K_ + slog * 8;
  const u16* Ag1 = Ag0 + (size_t)128 * K_;
  const u16* Bg0 = Bt + (size_t)(col0 + srow) * K_ + slog * 8;
  const u16* Bg1 = Bg0 + (size_t)128 * K_;

  // LDS read offsets (u16 units); swz(row) reduces to (l15 + l15/4) & 3
  const int cofs = ((quad ^ ((l15 + (l15 >> 2)) & 3)) << 3);
  const int aoff = (wm * 128 + l15) * 32 + cofs;
  const int boff = (wn * 64  + l15) * 32 + cofs;

  f32x4 acc[8][4];
  #pragma unroll
  for (int i = 0; i < 8; ++i)
    #pragma unroll
    for (int j = 0; j < 4; ++j)
      acc[i][j] = (f32x4){0.f, 0.f, 0.f, 0.f};

  // prologue: slices 0..2 in flight (12 loads), wait slice 0 (8 left in flight)
  #pragma unroll
  for (int t = 0; t < 3; ++t) {
    u16* dst = lds + t * 16384;
    gload16(Ag0 + t * 32, dst + tid * 8);
    gload16(Ag1 + t * 32, dst + 4096 + tid * 8);
    gload16(Bg0 + t * 32, dst + 8192 + tid * 8);
    gload16(Bg1 + t * 32, dst + 12288 + tid * 8);
  }
  asm volatile("s_waitcnt vmcnt(8)" ::: "memory");
  __builtin_amdgcn_s_barrier();
  asm volatile("" ::: "memory");

  // main loop: 32 slices of K=32; stage slice s+3 while computing s.
  #pragma unroll 1
  for (int s = 0; s < 29; ++s)
    MG_SLICE(s & 3, (s + 3) & 3, (s + 3) * 32, 1,
             asm volatile("s_waitcnt vmcnt(8)" ::: "memory"))
  MG_SLICE(1, 0, 0, 0, asm volatile("s_waitcnt vmcnt(4)" ::: "memory"))  // s=29
  MG_SLICE(2, 0, 0, 0, asm volatile("s_waitcnt vmcnt(0)" ::: "memory"))  // s=30
  MG_SLICE(3, 0, 0, 0, ((void)0))                                        // s=31

  if (MODE == 1 || MODE == 3) {
    // fp32 row-major epilogue (dword-coalesced scalar stores)
    const int rbase = row0 + wm * 128;
    #pragma unroll
    for (int j = 0; j < 4; ++j) {
      const int n = col0 + wn * 64 + j * 16 + l15;
      const float bn = bias[n];
      #pragma unroll
      for (int i = 0; i < 8; ++i)
        #pragma unroll
        for (int r = 0; r < 4; ++r) {
          const int row = rbase + i * 16 + quad * 4 + r;
          const size_t idx = (size_t)row * E_ + n;
          float v = acc[i][j][r] + bn;
          if (MODE == 1) Cf[idx] = v + resid[idx];
          else           Cf[idx] = v + Cf[idx];
        }
    }
    return;
  }

  // ---- bf16 epilogues via per-wave 16-KB LDS transpose -> 16-B coalesced stores ----
  u16* ep = lds + wid * 8192;                  // 128x64 u16, row stride 64
  const int nb0 = col0 + wn * 64;              // wave's 64-col window (64-aligned)

  if (MODE == 2) {
    #pragma unroll
    for (int j = 0; j < 4; ++j) {
      const float bn = bias[nb0 + j * 16 + l15];
      #pragma unroll
      for (int i = 0; i < 8; ++i)
        #pragma unroll
        for (int r = 0; r < 4; ++r)
          ep[(i*16 + quad*4 + r) * 64 + j*16 + l15] =
              f2bf(fmaxf(acc[i][j][r] + bn, 0.f));
    }
    __syncthreads();
    const int rbase = row0 + wm * 128;
    #pragma unroll
    for (int it = 0; it < 16; ++it) {
      const int tl = it * 8 + (lane >> 3), c = lane & 7;
      uint4 v = *(const uint4*)(ep + tl * 64 + c * 8);
      *(uint4*)(Cb + (size_t)(rbase + tl) * E_ + nb0 + c * 8) = v;
    }
    return;
  }

  // MODE 0: z = 0 (k), 1 (q): row-major (b,h,t,d). z = 2 (v): transposed (b,h,d,t).
  const int z = nb0 >> 10, hh = (nb0 >> 6) & 15;
  const int rows0 = row0 + wm * 128;
  const int bb = rows0 >> 8, tb0 = rows0 & 255;
  if (z < 2) {
    #pragma unroll
    for (int i = 0; i < 8; ++i)
      #pragma unroll
      for (int j = 0; j < 4; ++j)
        #pragma unroll
        for (int r = 0; r < 4; ++r)
          ep[(i*16 + quad*4 + r) * 64 + j*16 + l15] = f2bf(acc[i][j][r]);
    __syncthreads();
    u16* out = (z == 0 ? Cb : Cb2) + ((size_t)(bb * H_ + hh) * T_ + tb0) * HD_;
    #pragma unroll
    for (int it = 0; it < 16; ++it) {
      const int tl = it * 8 + (lane >> 3), c = lane & 7;
      uint4 v = *(const uint4*)(ep + tl * 64 + c * 8);
      *(uint4*)(out + (size_t)tl * HD_ + c * 8) = v;
    }
  } else {
    // write transposed [d][t'], 16B chunks swizzled: phys = (t'>>3) ^ (d&15)
    #pragma unroll
    for (int i = 0; i < 8; ++i)
      #pragma unroll
      for (int j = 0; j < 4; ++j)
        #pragma unroll
        for (int r = 0; r < 4; ++r) {
          const int tl = i*16 + quad*4 + r, d = j*16 + l15;
          const int phys = (tl >> 3) ^ (d & 15);
          ep[d * 128 + phys * 8 + (tl & 7)] = f2bf(acc[i][j][r]);
        }
    __syncthreads();
    u16* out = (u16*)Cf + ((size_t)(bb * H_ + hh) * HD_) * T_;
    #pragma unroll
    for (int it = 0; it < 16; ++it) {
      const int d = it * 4 + (lane >> 4), c = lane & 15;
      const int phys = c ^ (d & 15);
      uint4 v = *(const uint4*)(ep + d * 128 + phys * 8);
      *(uint4*)(out + (size_t)d * T_ + tb0 + c * 8) = v;
    }
  }
}

// ---------- MFMA flash attention: block = 4 bh's at one tblk (balanced waves) ----------
// scores[t][s] = k_t . q_s / 8 (K.Q^T per reference), causal s<=t.
// k,q bf16 (b,h,t,d); vt bf16 (b,h,d,t); out bf16 row-major (b,t,h*64+d).
__global__ __launch_bounds__(256) void fattn_kernel(
    const u16* __restrict__ kk_, const u16* __restrict__ qq_,
    const u16* __restrict__ vt_, u16* __restrict__ out)
{
  __shared__ __align__(16) u16 Pb[4][64 * 72];  // per-wave private, 9216 B each
  const int tid = threadIdx.x, lane = tid & 63, wv = tid >> 6;
  const int bh = blockIdx.x * 4 + wv;
  const int tblk = blockIdx.y;
  const int l15 = lane & 15, quad = lane >> 4;
  const u16* kb  = kk_ + (size_t)bh * (T_ * HD_);
  const u16* qb  = qq_ + (size_t)bh * (T_ * HD_);
  const u16* vtb = vt_ + (size_t)bh * (HD_ * T_);
  u16* Pw = Pb[wv];

  bf16x8 kf[4][2];
  #pragma unroll
  for (int i = 0; i < 4; ++i)
    #pragma unroll
    for (int c = 0; c < 2; ++c)
      kf[i][c] = *(const bf16x8*)(kb + (size_t)(tblk*64 + i*16 + l15) * HD_ + c*32 + quad*8);

  f32x4 o[4][4];
  float mrow[4][4], lrow[4][4];
  #pragma unroll
  for (int i = 0; i < 4; ++i) {
    #pragma unroll
    for (int j = 0; j < 4; ++j) o[i][j] = (f32x4){0.f, 0.f, 0.f, 0.f};
    #pragma unroll
    for (int r = 0; r < 4; ++r) { mrow[i][r] = -1e30f; lrow[i][r] = 0.f; }
  }

  for (int sb = 0; sb <= tblk; ++sb) {        // trip count uniform per block
    f32x4 S[4][4];
    #pragma unroll
    for (int j = 0; j < 4; ++j) {
      bf16x8 qf0 = *(const bf16x8*)(qb + (size_t)(sb*64 + j*16 + l15) * HD_ +      quad*8);
      bf16x8 qf1 = *(const bf16x8*)(qb + (size_t)(sb*64 + j*16 + l15) * HD_ + 32 + quad*8);
      #pragma unroll
      for (int i = 0; i < 4; ++i) {
        f32x4 t0 = __builtin_amdgcn_mfma_f32_16x16x32_bf16(kf[i][0], qf0,
                       (f32x4){0.f,0.f,0.f,0.f}, 0, 0, 0);
        S[i][j] = __builtin_amdgcn_mfma_f32_16x16x32_bf16(kf[i][1], qf1, t0, 0, 0, 0);
      }
    }
    #pragma unroll
    for (int i = 0; i < 4; ++i)
      #pragma unroll
      for (int j = 0; j < 4; ++j)
        #pragma unroll
        for (int r = 0; r < 4; ++r) {
          float val = S[i][j][r] * 0.125f;
          if (sb == tblk) {
            int tl = i*16 + quad*4 + r, sl = j*16 + l15;
            if (sl > tl) val = -1e30f;
          }
          S[i][j][r] = val;
        }
    #pragma unroll
    for (int i = 0; i < 4; ++i)
      #pragma unroll
      for (int r = 0; r < 4; ++r) {
        float mx = fmaxf(fmaxf(S[i][0][r], S[i][1][r]), fmaxf(S[i][2][r], S[i][3][r]));
        #pragma unroll
        for (int msk = 1; msk < 16; msk <<= 1) mx = fmaxf(mx, __shfl_xor(mx, msk));
        float mn = fmaxf(mrow[i][r], mx);
        float al = __expf(mrow[i][r] - mn);
        mrow[i][r] = mn;
        float sm = 0.f;
        #pragma unroll
        for (int j = 0; j < 4; ++j) {
          float p = __expf(S[i][j][r] - mn);
          S[i][j][r] = p;
          sm += p;
        }
        #pragma unroll
        for (int msk = 1; msk < 16; msk <<= 1) sm += __shfl_xor(sm, msk);
        lrow[i][r] = lrow[i][r] * al + sm;
        #pragma unroll
        for (int jd = 0; jd < 4; ++jd) o[i][jd][r] *= al;
      }
    #pragma unroll
    for (int i = 0; i < 4; ++i)
      #pragma unroll
      for (int j = 0; j < 4; ++j)
        #pragma unroll
        for (int r = 0; r < 4; ++r)
          Pw[(i*16 + quad*4 + r) * 72 + j*16 + l15] = f2bf_trunc(S[i][j][r]);
    __syncthreads();
    bf16x8 pf[4][2];
    #pragma unroll
    for (int i = 0; i < 4; ++i)
      #pragma unroll
      for (int c = 0; c < 2; ++c)
        pf[i][c] = *(const bf16x8*)(Pw + (i*16 + l15) * 72 + c*32 + quad*8);
    #pragma unroll
    for (int jd = 0; jd < 4; ++jd) {
      bf16x8 vf0 = *(const bf16x8*)(vtb + (size_t)(jd*16 + l15) * T_ + sb*64 +      quad*8);
      bf16x8 vf1 = *(const bf16x8*)(vtb + (size_t)(jd*16 + l15) * T_ + sb*64 + 32 + quad*8);
      #pragma unroll
      for (int i = 0; i < 4; ++i) {
        f32x4 t0 = __builtin_amdgcn_mfma_f32_16x16x32_bf16(pf[i][0], vf0, o[i][jd], 0, 0, 0);
        o[i][jd] = __builtin_amdgcn_mfma_f32_16x16x32_bf16(pf[i][1], vf1, t0, 0, 0, 0);
      }
    }
    __syncthreads();
  }

  #pragma unroll
  for (int i = 0; i < 4; ++i)
    #pragma unroll
    for (int r = 0; r < 4; ++r) {
      float inv = 1.0f / lrow[i][r];
      #pragma unroll
      for (int jd = 0; jd < 4; ++jd)
        Pw[(i*16 + quad*4 + r) * 72 + jd*16 + l15] = f2bf(o[i][jd][r] * inv);
    }
  __syncthreads();
  {
    const int b = bh >> 4, h = bh & 15;
    const uint4* pr = (const uint4*)(Pw + lane * 72);
    uint4* og = (uint4*)(out + ((size_t)(b * T_ + tblk*64 + lane)) * E_ + h * HD_);
    #pragma unroll
    for (int k = 0; k < 8; ++k) og[k] = pr[k];
  }
}

// ---------- launch ----------
extern "C" void kernel_launch(void* const* d_in, const int* in_sizes, int n_in,
                              void* d_out, int out_size, void* d_ws, size_t ws_size,
                              hipStream_t stream) {
  const float* x     = (const float*)d_in[0];
  const float* ln1g  = (const float*)d_in[1];
  const float* ln1b  = (const float*)d_in[2];
  const float* wk    = (const float*)d_in[3];
  const float* wq    = (const float*)d_in[4];
  const float* wv    = (const float*)d_in[5];
  const float* wproj = (const float*)d_in[6];
  const float* bproj = (const float*)d_in[7];
  const float* ln2g  = (const float*)d_in[8];
  const float* ln2b  = (const float*)d_in[9];
  const float* w1    = (const float*)d_in[10];
  const float* b1    = (const float*)d_in[11];
  const float* w2    = (const float*)d_in[12];
  const float* b2    = (const float*)d_in[13];
  float* outp = (float*)d_out;

  // ws (112 MB <= proven 128 MB):
  //  [0,6M) WqkvT | [6,8M) WprojT | [8,10M) W1T | [10,12M) W2T
  //  [16,48M) hb bf16 (LN1 out -> attn out)
  //  [48,80M) k bf16 (bhtd) -> h2 bf16 | [80,112M) q bf16 (bhtd) -> ff1 bf16
  // d_out (64MB): v^T bf16 (b,h,d,t) [0,32M) -> x1 fp32 (full) -> out (in-place)
  char* ws = (char*)d_ws;
  const size_t MB = 1024 * 1024;
  u16* wqkvT  = (u16*)(ws);
  u16* wprojT = (u16*)(ws + 6 * MB);
  u16* w1T    = (u16*)(ws + 8 * MB);
  u16* w2T    = (u16*)(ws + 10 * MB);
  u16* hb     = (u16*)(ws + 16 * MB);
  u16* kbuf   = (u16*)(ws + 48 * MB);
  u16* qbuf   = (u16*)(ws + 80 * MB);
  u16* vtbuf  = (u16*)d_out;                   // v^T (b,h,d,t) bf16

  convq_kernel<<<dim3(48, 16), 256, 0, stream>>>(wk, wq, wv, wqkvT);
  convt_kernel<<<dim3(16, 16), 256, 0, stream>>>(wproj, wprojT);
  convt_kernel<<<dim3(16, 16), 256, 0, stream>>>(w1, w1T);
  convt_kernel<<<dim3(16, 16), 256, 0, stream>>>(w2, w2T);

  // 1) hb = LN1(x) bf16
  ln_bf16_kernel<<<NTOK/4, 256, 0, stream>>>(x, ln1g, ln1b, hb);
  // 2) k,q bf16 (bhtd) + v^T bf16 (bhdt, d_out) = hb @ WqkvT^T   (256^2 tiles)
  mgemm_kernel<0><<<dim3(64, 12), 512, 0, stream>>>(
      hb, wqkvT, nullptr, nullptr, (float*)vtbuf, kbuf, qbuf);
  // 3) MFMA flash attention (balanced) -> bf16 row-major into hb
  fattn_kernel<<<dim3(B_*H_/4, 4), 256, 0, stream>>>(kbuf, qbuf, vtbuf, hb);
  // 4) x1 = x + attn @ wproj + bproj -> fp32 d_out (v^T dead)
  mgemm_kernel<1><<<dim3(64, 4), 512, 0, stream>>>(
      hb, wprojT, bproj, x, outp, nullptr, nullptr);
  // 5) h2 = LN2(x1) bf16 (over dead k)
  ln_bf16_kernel<<<NTOK/4, 256, 0, stream>>>(outp, ln2g, ln2b, kbuf);
  // 6) ff1 = relu(h2 @ w1 + b1) bf16 (over dead q)
  mgemm_kernel<2><<<dim3(64, 4), 512, 0, stream>>>(
      kbuf, w1T, b1, nullptr, nullptr, qbuf, nullptr);
  // 7) out = x1 + ff1 @ w2 + b2, in-place over d_out
  mgemm_kernel<3><<<dim3(64, 4), 512, 0, stream>>>(
      qbuf, w2T, b2, nullptr, outp, nullptr, nullptr);
}

// Round 2
// 527.037 us; speedup vs baseline: 1.0340x; 1.0340x over previous
//
#include <hip/hip_runtime.h>

typedef unsigned int u32;
typedef unsigned short u16;
typedef __attribute__((ext_vector_type(8))) short bf16x8;   // 8 bf16 in 4 VGPRs
typedef __attribute__((ext_vector_type(4))) float f32x4;

#define GLOBAL_AS __attribute__((address_space(1)))
#define LDS_AS    __attribute__((address_space(3)))

#define B_   64
#define T_   256
#define E_   1024
#define H_   16
#define HD_  64
#define NTOK (B_*T_)          // 16384
#define K_   1024
#define LNEPS 1e-5f

// ---------- bf16 helpers ----------
__device__ __forceinline__ u16 f2bf(float f){            // round-to-nearest-even
  u32 x = __float_as_uint(f);
  u32 r = x + 0x7fffu + ((x >> 16) & 1u);
  return (u16)(r >> 16);
}
__device__ __forceinline__ u16 f2bf_trunc(float f){      // truncate (P probs only)
  return (u16)(__float_as_uint(f) >> 16);
}
__device__ __forceinline__ u32 pack2(float a, float b){
  return (u32)f2bf(a) | ((u32)f2bf(b) << 16);
}

// async global->LDS, 16 B per lane (dest = wave-uniform base + lane*16)
__device__ __forceinline__ void gload16(const u16* g, u16* l){
  __builtin_amdgcn_global_load_lds((const GLOBAL_AS void*)g, (LDS_AS void*)l, 16, 0, 0);
}

// ---------- fused LayerNorm fp32 -> bf16, one wave per token ----------
__global__ __launch_bounds__(256) void ln_bf16_kernel(
    const float* __restrict__ x, const float* __restrict__ g,
    const float* __restrict__ b, u16* __restrict__ o)
{
  int lane  = threadIdx.x & 63;
  int token = (blockIdx.x << 2) + (threadIdx.x >> 6);
  const float4* xr = (const float4*)(x + (size_t)token * E_);
  float4 v[4];
  float s = 0.f, ss = 0.f;
  #pragma unroll
  for (int i = 0; i < 4; ++i){
    v[i] = xr[lane + 64 * i];
    s += v[i].x + v[i].y + v[i].z + v[i].w;
    ss = fmaf(v[i].x, v[i].x, fmaf(v[i].y, v[i].y,
         fmaf(v[i].z, v[i].z, fmaf(v[i].w, v[i].w, ss))));
  }
  #pragma unroll
  for (int off = 32; off > 0; off >>= 1){
    s  += __shfl_xor(s,  off);
    ss += __shfl_xor(ss, off);
  }
  float mu   = s * (1.f / E_);
  float var  = ss * (1.f / E_) - mu * mu;
  float rstd = rsqrtf(var + LNEPS);
  const float4* gr = (const float4*)g;
  const float4* br = (const float4*)b;
  uint2* orow = (uint2*)(o + (size_t)token * E_);
  #pragma unroll
  for (int i = 0; i < 4; ++i){
    float4 gg = gr[lane + 64 * i], bb = br[lane + 64 * i];
    float y0 = (v[i].x - mu) * rstd * gg.x + bb.x;
    float y1 = (v[i].y - mu) * rstd * gg.y + bb.y;
    float y2 = (v[i].z - mu) * rstd * gg.z + bb.z;
    float y3 = (v[i].w - mu) * rstd * gg.w + bb.w;
    orow[lane + 64 * i] = make_uint2(pack2(y0, y1), pack2(y2, y3));
  }
}

// ---------- weight prep: fragment-major B layout ----------
// GEMM B-operand is consumed as per-lane 16 B fragments:
//   elem(n, k) at o16 = (nb*32 + s)*2048 + j*512 + (quad*16 + l15)*8 + e
// where n = nb*64 + j*16 + l15, k = s*32 + quad*8 + e.
// A wave's per-slice fragment load is then a fully coalesced 1 KB global read.
__global__ __launch_bounds__(256) void convq_kernel(
    const float* __restrict__ wk, const float* __restrict__ wq,
    const float* __restrict__ wv, u16* __restrict__ o)
{
  __shared__ float tile[64 * 68];            // [k-local][d], +4 pad
  const int zh = blockIdx.x, z = zh >> 4, h = zh & 15;
  const int k0 = blockIdx.y << 6;
  const float* w = (z == 0 ? wk : z == 1 ? wq : wv) + (size_t)h * (E_ * HD_);
  const int t = threadIdx.x;
  {
    int kr = t >> 2, d0 = (t & 3) << 4;
    const float4* src = (const float4*)(w + (size_t)(k0 + kr) * HD_ + d0);
    #pragma unroll
    for (int i = 0; i < 4; ++i)
      *(float4*)(tile + kr * 68 + d0 + 4 * i) = src[i];
  }
  __syncthreads();
  {
    const size_t nb32 = (size_t)zh * 32 + (k0 >> 5);   // nb == zh
    #pragma unroll
    for (int u = 0; u < 2; ++u) {
      int cid = t * 2 + u;
      int dd = cid >> 3, kc = cid & 7;
      u32 wd[4];
      #pragma unroll
      for (int e2 = 0; e2 < 4; ++e2)
        wd[e2] = pack2(tile[(kc * 8 + 2 * e2) * 68 + dd],
                       tile[(kc * 8 + 2 * e2 + 1) * 68 + dd]);
      u16* dst = o + (nb32 + (kc >> 2)) * 2048 + (size_t)(dd >> 4) * 512
                   + (size_t)(((kc & 3) << 4) + (dd & 15)) * 8;
      *(uint4*)dst = make_uint4(wd[0], wd[1], wd[2], wd[3]);
    }
  }
}

// w [E][E] fp32, B(n,k) = w[k][n] -> fragment-major bf16
__global__ __launch_bounds__(256) void convt_kernel(
    const float* __restrict__ w, u16* __restrict__ o)
{
  __shared__ float tile[64 * 68];            // [k-local][n-local]
  const int n0 = blockIdx.x << 6, k0 = blockIdx.y << 6;
  const int t = threadIdx.x;
  {
    int kr = t >> 2, nn = (t & 3) << 4;
    const float4* src = (const float4*)(w + (size_t)(k0 + kr) * E_ + n0 + nn);
    #pragma unroll
    for (int i = 0; i < 4; ++i)
      *(float4*)(tile + kr * 68 + nn + 4 * i) = src[i];
  }
  __syncthreads();
  {
    const size_t nb32 = (size_t)(n0 >> 6) * 32 + (k0 >> 5);
    #pragma unroll
    for (int u = 0; u < 2; ++u) {
      int cid = t * 2 + u;
      int dd = cid >> 3, kc = cid & 7;
      u32 wd[4];
      #pragma unroll
      for (int e2 = 0; e2 < 4; ++e2)
        wd[e2] = pack2(tile[(kc * 8 + 2 * e2) * 68 + dd],
                       tile[(kc * 8 + 2 * e2 + 1) * 68 + dd]);
      u16* dst = o + (nb32 + (kc >> 2)) * 2048 + (size_t)(dd >> 4) * 512
                   + (size_t)(((kc & 3) << 4) + (dd & 15)) * 8;
      *(uint4*)dst = make_uint4(wd[0], wd[1], wd[2], wd[3]);
    }
  }
}

// ---------- MFMA GEMM: C(M x N) = A(M x 1024) * B^T, B fragment-major ----------
// 256x256 tile / 512 threads (8 waves 2M x 4N). A-ONLY LDS: 4-slot ring of
// [256 rows][32 k] bf16 slices (16 KB each), paired-row layout:
//   off16(r,k) = (r>>1)*64 + (((r&1)*4 + k/8) ^ ((r>>1)&7))*8 + (k&7)
// -> every consecutive-8-lane batch of a ds_read_b128 covers all 8 bank groups.
// global_load_lds dest stays lane-linear; swizzle applied on the global source.
// B comes from registers: coalesced 16 B/lane fragment loads (L2-resident
// weights), double-buffered 2 slices ahead (bE/bO). vmcnt counted, never 0
// in the main loop (12 steady; 10/8 in the tail).
// MODE 0: qkv -> k,q bf16 (b,h,t,d); v bf16 TRANSPOSED (b,h,d,t)
// MODE 1: proj -> Cf fp32 = acc + bias + resid              [row-major]
// MODE 2: ff1  -> Cb bf16 = relu(acc + bias)
// MODE 3: ff2  -> Cf fp32 = acc + bias + Cf (in-place residual)
#define MF4(I, AV, BV)                                                               \
  acc[I][0] = __builtin_amdgcn_mfma_f32_16x16x32_bf16(AV, BV[0], acc[I][0], 0, 0, 0);\
  acc[I][1] = __builtin_amdgcn_mfma_f32_16x16x32_bf16(AV, BV[1], acc[I][1], 0, 0, 0);\
  acc[I][2] = __builtin_amdgcn_mfma_f32_16x16x32_bf16(AV, BV[2], acc[I][2], 0, 0, 0);\
  acc[I][3] = __builtin_amdgcn_mfma_f32_16x16x32_bf16(AV, BV[3], acc[I][3], 0, 0, 0);

#define BLOADS(BV, SS) {                                                      \
    const u16* bp_ = Bp + (size_t)(SS) * 2048;                                \
    BV[0] = *(const bf16x8*)(bp_);                                            \
    BV[1] = *(const bf16x8*)(bp_ + 512);                                      \
    BV[2] = *(const bf16x8*)(bp_ + 1024);                                     \
    BV[3] = *(const bf16x8*)(bp_ + 1536);                                     \
  }

#define MSLICE(SLOT, DST, KA, DO_STAGE, BV, BL, VM) {                         \
    const u16* As_ = lds + (SLOT) * 8192;                                     \
    bf16x8 a0 = *(const bf16x8*)(As_ + aoffb);                                \
    bf16x8 a1 = *(const bf16x8*)(As_ + aoffb + 512);                          \
    bf16x8 a2 = *(const bf16x8*)(As_ + aoffb + 1024);                         \
    bf16x8 a3 = *(const bf16x8*)(As_ + aoffb + 1536);                         \
    if (DO_STAGE) {                                                           \
      u16* d_ = lds + (DST) * 8192;                                           \
      gload16(Ag0 + (KA), d_ + tid * 8);                                      \
      gload16(Ag1 + (KA), d_ + 4096 + tid * 8);                               \
    }                                                                         \
    __builtin_amdgcn_s_barrier();                                             \
    asm volatile("s_waitcnt lgkmcnt(0)" ::: "memory");                        \
    __builtin_amdgcn_sched_barrier(0);                                        \
    __builtin_amdgcn_s_setprio(1);                                            \
    MF4(0, a0, BV) MF4(1, a1, BV) MF4(2, a2, BV) MF4(3, a3, BV)               \
    __builtin_amdgcn_s_setprio(0);                                            \
    a0 = *(const bf16x8*)(As_ + aoffb + 2048);                                \
    a1 = *(const bf16x8*)(As_ + aoffb + 2560);                                \
    a2 = *(const bf16x8*)(As_ + aoffb + 3072);                                \
    a3 = *(const bf16x8*)(As_ + aoffb + 3584);                                \
    asm volatile("s_waitcnt lgkmcnt(0)" ::: "memory");                        \
    __builtin_amdgcn_sched_barrier(0);                                        \
    __builtin_amdgcn_s_setprio(1);                                            \
    MF4(4, a0, BV) MF4(5, a1, BV) MF4(6, a2, BV) MF4(7, a3, BV)               \
    __builtin_amdgcn_s_setprio(0);                                            \
    BL;                                                                       \
    VM;                                                                       \
    __builtin_amdgcn_s_barrier();                                             \
    asm volatile("" ::: "memory");                                            \
  }

#define VM12 asm volatile("s_waitcnt vmcnt(12)" ::: "memory")
#define VM10 asm volatile("s_waitcnt vmcnt(10)" ::: "memory")
#define VM8  asm volatile("s_waitcnt vmcnt(8)"  ::: "memory")

template<int MODE>
__global__ __launch_bounds__(512, 2) void mgemm_kernel(
    const u16* __restrict__ A, const u16* __restrict__ Bt,
    const float* __restrict__ bias, const float* __restrict__ resid,
    float* __restrict__ Cf, u16* __restrict__ Cb, u16* __restrict__ Cb2)
{
  __shared__ __align__(16) u16 lds[65536];   // 64 KB A-ring + epilogue reuse

  const int tid = threadIdx.x, lane = tid & 63, wid = tid >> 6;
  const int wm = wid >> 2, wn = wid & 3;
  const int l15 = lane & 15, quad = lane >> 4;

  // XCD-aware mapping: XCD x owns 8 M-tiles (4 MB A-panel, L2-resident),
  // all XCDs sweep N-columns in lockstep (B panels L3-shared).
  const int b = (int)blockIdx.x;
  const int xcd = b & 7, ib = b >> 3;
  const int row0 = ((xcd << 3) + (ib & 7)) << 8;
  const int col0 = (ib >> 3) << 8;

  // A staging: pre-swizzled global source, lane-linear LDS dest.
  const int sc   = (tid & 7) ^ ((tid >> 3) & 7);
  const int srow = 2 * (tid >> 3) + (sc >> 2);
  const int skof = (sc & 3) << 3;
  const u16* Ag0 = A + (size_t)(row0 + srow) * K_ + skof;
  const u16* Ag1 = Ag0 + (size_t)128 * K_;

  // A fragment read offsets (paired-row + 3-bit XOR)
  const int rhalf = l15 >> 1;
  const int cph   = ((((l15 & 1) << 2) | quad) ^ rhalf);
  const int aoffb = wm * 4096 + rhalf * 64 + cph * 8;

  // B fragment-major pointer: nb = col0/64 + wn
  const u16* Bp = Bt + (size_t)((col0 >> 6) + wn) * 65536 + lane * 8;

  f32x4 acc[8][4];
  #pragma unroll
  for (int i = 0; i < 8; ++i)
    #pragma unroll
    for (int j = 0; j < 4; ++j)
      acc[i][j] = (f32x4){0.f, 0.f, 0.f, 0.f};

  bf16x8 bE[4], bO[4];

  // prologue: A slices 0..2 (6 loads) + B(0),B(1) (8 loads); drain A0.
  #pragma unroll
  for (int t3 = 0; t3 < 3; ++t3) {
    u16* d_ = lds + t3 * 8192;
    gload16(Ag0 + t3 * 32, d_ + tid * 8);
    gload16(Ag1 + t3 * 32, d_ + 4096 + tid * 8);
  }
  BLOADS(bE, 0)
  BLOADS(bO, 1)
  asm volatile("s_waitcnt vmcnt(12)" ::: "memory");
  __builtin_amdgcn_s_barrier();
  asm volatile("" ::: "memory");

  // main: 32 slices of K=32; stage A(s+3), load B(s+2) to regs.
  #pragma unroll 1
  for (int s = 0; s < 28; s += 2) {
    MSLICE(s & 3, (s + 3) & 3, (s + 3) * 32, 1, bE, BLOADS(bE, s + 2), VM12)
    MSLICE((s + 1) & 3, (s + 4) & 3, (s + 4) * 32, 1, bO, BLOADS(bO, s + 3), VM12)
  }
  MSLICE(0, 3, 31 * 32, 1, bE, BLOADS(bE, 30), VM12)   // s=28
  MSLICE(1, 0, 0,       0, bO, BLOADS(bO, 31), VM10)   // s=29
  MSLICE(2, 0, 0,       0, bE, (void)0,        VM8 )   // s=30
  MSLICE(3, 0, 0,       0, bO, (void)0,        (void)0)// s=31

  if (MODE == 1 || MODE == 3) {
    // fp32 row-major epilogue (dword-coalesced scalar stores)
    const int rbase = row0 + wm * 128;
    #pragma unroll
    for (int j = 0; j < 4; ++j) {
      const int n = col0 + wn * 64 + j * 16 + l15;
      const float bn = bias[n];
      #pragma unroll
      for (int i = 0; i < 8; ++i)
        #pragma unroll
        for (int r = 0; r < 4; ++r) {
          const int row = rbase + i * 16 + quad * 4 + r;
          const size_t idx = (size_t)row * E_ + n;
          float v = acc[i][j][r] + bn;
          if (MODE == 1) Cf[idx] = v + resid[idx];
          else           Cf[idx] = v + Cf[idx];
        }
    }
    return;
  }

  // ---- bf16 epilogues via per-wave 16-KB LDS transpose -> 16-B coalesced stores ----
  u16* ep = lds + wid * 8192;                  // 128x64 u16, row stride 64
  const int nb0 = col0 + wn * 64;              // wave's 64-col window (64-aligned)

  if (MODE == 2) {
    #pragma unroll
    for (int j = 0; j < 4; ++j) {
      const float bn = bias[nb0 + j * 16 + l15];
      #pragma unroll
      for (int i = 0; i < 8; ++i)
        #pragma unroll
        for (int r = 0; r < 4; ++r)
          ep[(i*16 + quad*4 + r) * 64 + j*16 + l15] =
              f2bf(fmaxf(acc[i][j][r] + bn, 0.f));
    }
    __syncthreads();
    const int rbase = row0 + wm * 128;
    #pragma unroll
    for (int it = 0; it < 16; ++it) {
      const int tl = it * 8 + (lane >> 3), c = lane & 7;
      uint4 v = *(const uint4*)(ep + tl * 64 + c * 8);
      *(uint4*)(Cb + (size_t)(rbase + tl) * E_ + nb0 + c * 8) = v;
    }
    return;
  }

  // MODE 0: z = 0 (k), 1 (q): row-major (b,h,t,d). z = 2 (v): transposed (b,h,d,t).
  const int z = nb0 >> 10, hh = (nb0 >> 6) & 15;
  const int rows0 = row0 + wm * 128;
  const int bb = rows0 >> 8, tb0 = rows0 & 255;
  if (z < 2) {
    #pragma unroll
    for (int i = 0; i < 8; ++i)
      #pragma unroll
      for (int j = 0; j < 4; ++j)
        #pragma unroll
        for (int r = 0; r < 4; ++r)
          ep[(i*16 + quad*4 + r) * 64 + j*16 + l15] = f2bf(acc[i][j][r]);
    __syncthreads();
    u16* out = (z == 0 ? Cb : Cb2) + ((size_t)(bb * H_ + hh) * T_ + tb0) * HD_;
    #pragma unroll
    for (int it = 0; it < 16; ++it) {
      const int tl = it * 8 + (lane >> 3), c = lane & 7;
      uint4 v = *(const uint4*)(ep + tl * 64 + c * 8);
      *(uint4*)(out + (size_t)tl * HD_ + c * 8) = v;
    }
  } else {
    // write transposed [d][t'], 16B chunks swizzled: phys = (t'>>3) ^ (d&15)
    #pragma unroll
    for (int i = 0; i < 8; ++i)
      #pragma unroll
      for (int j = 0; j < 4; ++j)
        #pragma unroll
        for (int r = 0; r < 4; ++r) {
          const int tl = i*16 + quad*4 + r, d = j*16 + l15;
          const int phys = (tl >> 3) ^ (d & 15);
          ep[d * 128 + phys * 8 + (tl & 7)] = f2bf(acc[i][j][r]);
        }
    __syncthreads();
    u16* out = (u16*)Cf + ((size_t)(bb * H_ + hh) * HD_) * T_;
    #pragma unroll
    for (int it = 0; it < 16; ++it) {
      const int d = it * 4 + (lane >> 4), c = lane & 15;
      const int phys = c ^ (d & 15);
      uint4 v = *(const uint4*)(ep + d * 128 + phys * 8);
      *(uint4*)(out + (size_t)d * T_ + tb0 + c * 8) = v;
    }
  }
}

// ---------- MFMA flash attention: block = 4 bh's at one tblk (balanced waves) ----------
// scores[t][s] = k_t . q_s / 8 (K.Q^T per reference), causal s<=t.
// k,q bf16 (b,h,t,d); vt bf16 (b,h,d,t); out bf16 row-major (b,t,h*64+d).
__global__ __launch_bounds__(256) void fattn_kernel(
    const u16* __restrict__ kk_, const u16* __restrict__ qq_,
    const u16* __restrict__ vt_, u16* __restrict__ out)
{
  __shared__ __align__(16) u16 Pb[4][64 * 72];  // per-wave private, 9216 B each
  const int tid = threadIdx.x, lane = tid & 63, wv = tid >> 6;
  const int bh = blockIdx.x * 4 + wv;
  const int tblk = blockIdx.y;
  const int l15 = lane & 15, quad = lane >> 4;
  const u16* kb  = kk_ + (size_t)bh * (T_ * HD_);
  const u16* qb  = qq_ + (size_t)bh * (T_ * HD_);
  const u16* vtb = vt_ + (size_t)bh * (HD_ * T_);
  u16* Pw = Pb[wv];

  bf16x8 kf[4][2];
  #pragma unroll
  for (int i = 0; i < 4; ++i)
    #pragma unroll
    for (int c = 0; c < 2; ++c)
      kf[i][c] = *(const bf16x8*)(kb + (size_t)(tblk*64 + i*16 + l15) * HD_ + c*32 + quad*8);

  f32x4 o[4][4];
  float mrow[4][4], lrow[4][4];
  #pragma unroll
  for (int i = 0; i < 4; ++i) {
    #pragma unroll
    for (int j = 0; j < 4; ++j) o[i][j] = (f32x4){0.f, 0.f, 0.f, 0.f};
    #pragma unroll
    for (int r = 0; r < 4; ++r) { mrow[i][r] = -1e30f; lrow[i][r] = 0.f; }
  }

  for (int sb = 0; sb <= tblk; ++sb) {        // trip count uniform per block
    f32x4 S[4][4];
    #pragma unroll
    for (int j = 0; j < 4; ++j) {
      bf16x8 qf0 = *(const bf16x8*)(qb + (size_t)(sb*64 + j*16 + l15) * HD_ +      quad*8);
      bf16x8 qf1 = *(const bf16x8*)(qb + (size_t)(sb*64 + j*16 + l15) * HD_ + 32 + quad*8);
      #pragma unroll
      for (int i = 0; i < 4; ++i) {
        f32x4 t0 = __builtin_amdgcn_mfma_f32_16x16x32_bf16(kf[i][0], qf0,
                       (f32x4){0.f,0.f,0.f,0.f}, 0, 0, 0);
        S[i][j] = __builtin_amdgcn_mfma_f32_16x16x32_bf16(kf[i][1], qf1, t0, 0, 0, 0);
      }
    }
    #pragma unroll
    for (int i = 0; i < 4; ++i)
      #pragma unroll
      for (int j = 0; j < 4; ++j)
        #pragma unroll
        for (int r = 0; r < 4; ++r) {
          float val = S[i][j][r] * 0.125f;
          if (sb == tblk) {
            int tl = i*16 + quad*4 + r, sl = j*16 + l15;
            if (sl > tl) val = -1e30f;
          }
          S[i][j][r] = val;
        }
    #pragma unroll
    for (int i = 0; i < 4; ++i)
      #pragma unroll
      for (int r = 0; r < 4; ++r) {
        float mx = fmaxf(fmaxf(S[i][0][r], S[i][1][r]), fmaxf(S[i][2][r], S[i][3][r]));
        #pragma unroll
        for (int msk = 1; msk < 16; msk <<= 1) mx = fmaxf(mx, __shfl_xor(mx, msk));
        float mn = fmaxf(mrow[i][r], mx);
        float al = __expf(mrow[i][r] - mn);
        mrow[i][r] = mn;
        float sm = 0.f;
        #pragma unroll
        for (int j = 0; j < 4; ++j) {
          float p = __expf(S[i][j][r] - mn);
          S[i][j][r] = p;
          sm += p;
        }
        #pragma unroll
        for (int msk = 1; msk < 16; msk <<= 1) sm += __shfl_xor(sm, msk);
        lrow[i][r] = lrow[i][r] * al + sm;
        #pragma unroll
        for (int jd = 0; jd < 4; ++jd) o[i][jd][r] *= al;
      }
    #pragma unroll
    for (int i = 0; i < 4; ++i)
      #pragma unroll
      for (int j = 0; j < 4; ++j)
        #pragma unroll
        for (int r = 0; r < 4; ++r)
          Pw[(i*16 + quad*4 + r) * 72 + j*16 + l15] = f2bf_trunc(S[i][j][r]);
    __syncthreads();
    bf16x8 pf[4][2];
    #pragma unroll
    for (int i = 0; i < 4; ++i)
      #pragma unroll
      for (int c = 0; c < 2; ++c)
        pf[i][c] = *(const bf16x8*)(Pw + (i*16 + l15) * 72 + c*32 + quad*8);
    #pragma unroll
    for (int jd = 0; jd < 4; ++jd) {
      bf16x8 vf0 = *(const bf16x8*)(vtb + (size_t)(jd*16 + l15) * T_ + sb*64 +      quad*8);
      bf16x8 vf1 = *(const bf16x8*)(vtb + (size_t)(jd*16 + l15) * T_ + sb*64 + 32 + quad*8);
      #pragma unroll
      for (int i = 0; i < 4; ++i) {
        f32x4 t0 = __builtin_amdgcn_mfma_f32_16x16x32_bf16(pf[i][0], vf0, o[i][jd], 0, 0, 0);
        o[i][jd] = __builtin_amdgcn_mfma_f32_16x16x32_bf16(pf[i][1], vf1, t0, 0, 0, 0);
      }
    }
    __syncthreads();
  }

  #pragma unroll
  for (int i = 0; i < 4; ++i)
    #pragma unroll
    for (int r = 0; r < 4; ++r) {
      float inv = 1.0f / lrow[i][r];
      #pragma unroll
      for (int jd = 0; jd < 4; ++jd)
        Pw[(i*16 + quad*4 + r) * 72 + jd*16 + l15] = f2bf(o[i][jd][r] * inv);
    }
  __syncthreads();
  {
    const int b = bh >> 4, h = bh & 15;
    const uint4* pr = (const uint4*)(Pw + lane * 72);
    uint4* og = (uint4*)(out + ((size_t)(b * T_ + tblk*64 + lane)) * E_ + h * HD_);
    #pragma unroll
    for (int k = 0; k < 8; ++k) og[k] = pr[k];
  }
}

// ---------- launch ----------
extern "C" void kernel_launch(void* const* d_in, const int* in_sizes, int n_in,
                              void* d_out, int out_size, void* d_ws, size_t ws_size,
                              hipStream_t stream) {
  const float* x     = (const float*)d_in[0];
  const float* ln1g  = (const float*)d_in[1];
  const float* ln1b  = (const float*)d_in[2];
  const float* wk    = (const float*)d_in[3];
  const float* wq    = (const float*)d_in[4];
  const float* wv    = (const float*)d_in[5];
  const float* wproj = (const float*)d_in[6];
  const float* bproj = (const float*)d_in[7];
  const float* ln2g  = (const float*)d_in[8];
  const float* ln2b  = (const float*)d_in[9];
  const float* w1    = (const float*)d_in[10];
  const float* b1    = (const float*)d_in[11];
  const float* w2    = (const float*)d_in[12];
  const float* b2    = (const float*)d_in[13];
  float* outp = (float*)d_out;

  // ws (112 MB <= proven 128 MB):
  //  [0,6M) WqkvF | [6,8M) WprojF | [8,10M) W1F | [10,12M) W2F   (fragment-major)
  //  [16,48M) hb bf16 (LN1 out -> attn out)
  //  [48,80M) k bf16 (bhtd) -> h2 bf16 | [80,112M) q bf16 (bhtd) -> ff1 bf16
  // d_out (64MB): v^T bf16 (b,h,d,t) [0,32M) -> x1 fp32 (full) -> out (in-place)
  char* ws = (char*)d_ws;
  const size_t MB = 1024 * 1024;
  u16* wqkvT  = (u16*)(ws);
  u16* wprojT = (u16*)(ws + 6 * MB);
  u16* w1T    = (u16*)(ws + 8 * MB);
  u16* w2T    = (u16*)(ws + 10 * MB);
  u16* hb     = (u16*)(ws + 16 * MB);
  u16* kbuf   = (u16*)(ws + 48 * MB);
  u16* qbuf   = (u16*)(ws + 80 * MB);
  u16* vtbuf  = (u16*)d_out;                   // v^T (b,h,d,t) bf16

  convq_kernel<<<dim3(48, 16), 256, 0, stream>>>(wk, wq, wv, wqkvT);
  convt_kernel<<<dim3(16, 16), 256, 0, stream>>>(wproj, wprojT);
  convt_kernel<<<dim3(16, 16), 256, 0, stream>>>(w1, w1T);
  convt_kernel<<<dim3(16, 16), 256, 0, stream>>>(w2, w2T);

  // 1) hb = LN1(x) bf16
  ln_bf16_kernel<<<NTOK/4, 256, 0, stream>>>(x, ln1g, ln1b, hb);
  // 2) k,q bf16 (bhtd) + v^T bf16 (bhdt, d_out) = hb @ WqkvF
  mgemm_kernel<0><<<768, 512, 0, stream>>>(
      hb, wqkvT, nullptr, nullptr, (float*)vtbuf, kbuf, qbuf);
  // 3) MFMA flash attention (balanced) -> bf16 row-major into hb
  fattn_kernel<<<dim3(B_*H_/4, 4), 256, 0, stream>>>(kbuf, qbuf, vtbuf, hb);
  // 4) x1 = x + attn @ wproj + bproj -> fp32 d_out (v^T dead)
  mgemm_kernel<1><<<256, 512, 0, stream>>>(
      hb, wprojT, bproj, x, outp, nullptr, nullptr);
  // 5) h2 = LN2(x1) bf16 (over dead k)
  ln_bf16_kernel<<<NTOK/4, 256, 0, stream>>>(outp, ln2g, ln2b, kbuf);
  // 6) ff1 = relu(h2 @ w1 + b1) bf16 (over dead q)
  mgemm_kernel<2><<<256, 512, 0, stream>>>(
      kbuf, w1T, b1, nullptr, nullptr, qbuf, nullptr);
  // 7) out = x1 + ff1 @ w2 + b2, in-place over d_out
  mgemm_kernel<3><<<256, 512, 0, stream>>>(
      qbuf, w2T, b2, nullptr, outp, nullptr, nullptr);
}

// Round 4
// 513.068 us; speedup vs baseline: 1.0622x; 1.0272x over previous
//
#include <hip/hip_runtime.h>

typedef unsigned int u32;
typedef unsigned short u16;
typedef __attribute__((ext_vector_type(8))) short bf16x8;   // 8 bf16 in 4 VGPRs
typedef __attribute__((ext_vector_type(4))) float f32x4;

#define GLOBAL_AS __attribute__((address_space(1)))
#define LDS_AS    __attribute__((address_space(3)))

#define B_   64
#define T_   256
#define E_   1024
#define H_   16
#define HD_  64
#define NTOK (B_*T_)          // 16384
#define K_   1024
#define LNEPS 1e-5f

// ---------- bf16 helpers ----------
__device__ __forceinline__ u16 f2bf(float f){            // round-to-nearest-even
  u32 x = __float_as_uint(f);
  u32 r = x + 0x7fffu + ((x >> 16) & 1u);
  return (u16)(r >> 16);
}
__device__ __forceinline__ u16 f2bf_trunc(float f){      // truncate (P probs only)
  return (u16)(__float_as_uint(f) >> 16);
}
__device__ __forceinline__ u32 pack2(float a, float b){
  return (u32)f2bf(a) | ((u32)f2bf(b) << 16);
}

// async global->LDS, 16 B per lane (dest = wave-uniform base + lane*16)
__device__ __forceinline__ void gload16(const u16* g, u16* l){
  __builtin_amdgcn_global_load_lds((const GLOBAL_AS void*)g, (LDS_AS void*)l, 16, 0, 0);
}

// ---------- fused LayerNorm fp32 -> bf16, one wave per token ----------
__global__ __launch_bounds__(256) void ln_bf16_kernel(
    const float* __restrict__ x, const float* __restrict__ g,
    const float* __restrict__ b, u16* __restrict__ o)
{
  int lane  = threadIdx.x & 63;
  int token = (blockIdx.x << 2) + (threadIdx.x >> 6);
  const float4* xr = (const float4*)(x + (size_t)token * E_);
  float4 v[4];
  float s = 0.f, ss = 0.f;
  #pragma unroll
  for (int i = 0; i < 4; ++i){
    v[i] = xr[lane + 64 * i];
    s += v[i].x + v[i].y + v[i].z + v[i].w;
    ss = fmaf(v[i].x, v[i].x, fmaf(v[i].y, v[i].y,
         fmaf(v[i].z, v[i].z, fmaf(v[i].w, v[i].w, ss))));
  }
  #pragma unroll
  for (int off = 32; off > 0; off >>= 1){
    s  += __shfl_xor(s,  off);
    ss += __shfl_xor(ss, off);
  }
  float mu   = s * (1.f / E_);
  float var  = ss * (1.f / E_) - mu * mu;
  float rstd = rsqrtf(var + LNEPS);
  const float4* gr = (const float4*)g;
  const float4* br = (const float4*)b;
  uint2* orow = (uint2*)(o + (size_t)token * E_);
  #pragma unroll
  for (int i = 0; i < 4; ++i){
    float4 gg = gr[lane + 64 * i], bb = br[lane + 64 * i];
    float y0 = (v[i].x - mu) * rstd * gg.x + bb.x;
    float y1 = (v[i].y - mu) * rstd * gg.y + bb.y;
    float y2 = (v[i].z - mu) * rstd * gg.z + bb.z;
    float y3 = (v[i].w - mu) * rstd * gg.w + bb.w;
    orow[lane + 64 * i] = make_uint2(pack2(y0, y1), pack2(y2, y3));
  }
}

// ---------- weight prep: fragment-major B layout ----------
// elem(n, k) at o16 = (nb*32 + s)*2048 + j*512 + (quad*16 + l15)*8 + e
// where n = nb*64 + j*16 + l15, k = s*32 + quad*8 + e.
__global__ __launch_bounds__(256) void convq_kernel(
    const float* __restrict__ wk, const float* __restrict__ wq,
    const float* __restrict__ wv, u16* __restrict__ o)
{
  __shared__ float tile[64 * 68];            // [k-local][d], +4 pad
  const int zh = blockIdx.x, z = zh >> 4, h = zh & 15;
  const int k0 = blockIdx.y << 6;
  const float* w = (z == 0 ? wk : z == 1 ? wq : wv) + (size_t)h * (E_ * HD_);
  const int t = threadIdx.x;
  {
    int kr = t >> 2, d0 = (t & 3) << 4;
    const float4* src = (const float4*)(w + (size_t)(k0 + kr) * HD_ + d0);
    #pragma unroll
    for (int i = 0; i < 4; ++i)
      *(float4*)(tile + kr * 68 + d0 + 4 * i) = src[i];
  }
  __syncthreads();
  {
    const size_t nb32 = (size_t)zh * 32 + (k0 >> 5);   // nb == zh
    #pragma unroll
    for (int u = 0; u < 2; ++u) {
      int cid = t * 2 + u;
      int dd = cid >> 3, kc = cid & 7;
      u32 wd[4];
      #pragma unroll
      for (int e2 = 0; e2 < 4; ++e2)
        wd[e2] = pack2(tile[(kc * 8 + 2 * e2) * 68 + dd],
                       tile[(kc * 8 + 2 * e2 + 1) * 68 + dd]);
      u16* dst = o + (nb32 + (kc >> 2)) * 2048 + (size_t)(dd >> 4) * 512
                   + (size_t)(((kc & 3) << 4) + (dd & 15)) * 8;
      *(uint4*)dst = make_uint4(wd[0], wd[1], wd[2], wd[3]);
    }
  }
}

// w [E][E] fp32, B(n,k) = w[k][n] -> fragment-major bf16
__global__ __launch_bounds__(256) void convt_kernel(
    const float* __restrict__ w, u16* __restrict__ o)
{
  __shared__ float tile[64 * 68];            // [k-local][n-local]
  const int n0 = blockIdx.x << 6, k0 = blockIdx.y << 6;
  const int t = threadIdx.x;
  {
    int kr = t >> 2, nn = (t & 3) << 4;
    const float4* src = (const float4*)(w + (size_t)(k0 + kr) * E_ + n0 + nn);
    #pragma unroll
    for (int i = 0; i < 4; ++i)
      *(float4*)(tile + kr * 68 + nn + 4 * i) = src[i];
  }
  __syncthreads();
  {
    const size_t nb32 = (size_t)(n0 >> 6) * 32 + (k0 >> 5);
    #pragma unroll
    for (int u = 0; u < 2; ++u) {
      int cid = t * 2 + u;
      int dd = cid >> 3, kc = cid & 7;
      u32 wd[4];
      #pragma unroll
      for (int e2 = 0; e2 < 4; ++e2)
        wd[e2] = pack2(tile[(kc * 8 + 2 * e2) * 68 + dd],
                       tile[(kc * 8 + 2 * e2 + 1) * 68 + dd]);
      u16* dst = o + (nb32 + (kc >> 2)) * 2048 + (size_t)(dd >> 4) * 512
                   + (size_t)(((kc & 3) << 4) + (dd & 15)) * 8;
      *(uint4*)dst = make_uint4(wd[0], wd[1], wd[2], wd[3]);
    }
  }
}

// ---------- MFMA GEMM: C(M x N) = A(M x 1024) * B^T, B fragment-major ----------
// 256x256 tile / 512 threads (8 waves 2M x 4N). A-only LDS 4-slot ring (BK=32).
// Software-pipelined register loads: phase A of slice s issues ds_reads for
// row-half 1 then MFMAs row-half 0 (reads drain under MFMAs, compiler emits
// counted lgkmcnt); phase B issues ds_reads for slice s+1's row-half 0 (slot
// valid: VM10 confirms each A-stage 2 slices ahead) then MFMAs row-half 1.
// One barrier per slice + sched_barrier(0) pin. B-fragments from global to
// regs (L2-resident weights), loaded after their last use, 2 slices ahead.
// MODE 0: qkv -> k,q bf16 (b,h,t,d); v bf16 TRANSPOSED (b,h,d,t)
// MODE 1: proj -> Cf fp32 = acc + bias + resid              [row-major]
// MODE 2: ff1  -> Cb bf16 = relu(acc + bias)
// MODE 3: ff2  -> Cf fp32 = acc + bias + Cf (in-place residual)
#define MF4(I, AV, BV)                                                               \
  acc[I][0] = __builtin_amdgcn_mfma_f32_16x16x32_bf16(AV, BV[0], acc[I][0], 0, 0, 0);\
  acc[I][1] = __builtin_amdgcn_mfma_f32_16x16x32_bf16(AV, BV[1], acc[I][1], 0, 0, 0);\
  acc[I][2] = __builtin_amdgcn_mfma_f32_16x16x32_bf16(AV, BV[2], acc[I][2], 0, 0, 0);\
  acc[I][3] = __builtin_amdgcn_mfma_f32_16x16x32_bf16(AV, BV[3], acc[I][3], 0, 0, 0);

#define BLOADS(BV, SS) {                                                      \
    const u16* bp_ = Bp + (size_t)(SS) * 2048;                                \
    BV[0] = *(const bf16x8*)(bp_);                                            \
    BV[1] = *(const bf16x8*)(bp_ + 512);                                      \
    BV[2] = *(const bf16x8*)(bp_ + 1024);                                     \
    BV[3] = *(const bf16x8*)(bp_ + 1536);                                     \
  }

// SLOT: ring slot of slice s. NSLOT: slot of slice s+1 (phase-B lookahead read).
// ACUR: row-half-0 regs of slice s (read during previous slice's phase B).
// ATMP: row-half-1 regs (read phase A).  ANXT: next slice's row-half 0.
#define MSLICE2(SLOT, NSLOT, KA, DO_STAGE, DO_NXT, DO_BL, BS, ACUR, ATMP, ANXT, BV, BNV, VM) { \
    const u16* As_ = lds + (SLOT) * 8192;                                     \
    /* phase A: issue row-half-1 reads, stage A(s+3), MFMA row-half 0 */      \
    ATMP[0] = *(const bf16x8*)(As_ + aoffb + 2048);                           \
    ATMP[1] = *(const bf16x8*)(As_ + aoffb + 2560);                           \
    ATMP[2] = *(const bf16x8*)(As_ + aoffb + 3072);                           \
    ATMP[3] = *(const bf16x8*)(As_ + aoffb + 3584);                           \
    if (DO_STAGE) {                                                           \
      u16* d_ = lds + (((SLOT) + 3) & 3) * 8192;                              \
      gload16(Ag0 + (KA), d_ + tid * 8);                                      \
      gload16(Ag1 + (KA), d_ + 4096 + tid * 8);                               \
    }                                                                         \
    __builtin_amdgcn_s_setprio(1);                                            \
    MF4(0, ACUR[0], BV) MF4(1, ACUR[1], BV) MF4(2, ACUR[2], BV) MF4(3, ACUR[3], BV) \
    __builtin_amdgcn_s_setprio(0);                                            \
    /* phase B: issue next slice row-half-0 reads, MFMA row-half 1 */         \
    if (DO_NXT) {                                                             \
      const u16* An_ = lds + (NSLOT) * 8192;                                  \
      ANXT[0] = *(const bf16x8*)(An_ + aoffb);                                \
      ANXT[1] = *(const bf16x8*)(An_ + aoffb + 512);                          \
      ANXT[2] = *(const bf16x8*)(An_ + aoffb + 1024);                         \
      ANXT[3] = *(const bf16x8*)(An_ + aoffb + 1536);                         \
    }                                                                         \
    __builtin_amdgcn_s_setprio(1);                                            \
    MF4(4, ATMP[0], BV) MF4(5, ATMP[1], BV) MF4(6, ATMP[2], BV) MF4(7, ATMP[3], BV) \
    __builtin_amdgcn_s_setprio(0);                                            \
    if (DO_BL) { BLOADS(BNV, BS) }                                            \
    VM;                                                                       \
    __builtin_amdgcn_s_barrier();                                             \
    __builtin_amdgcn_sched_barrier(0);                                        \
    asm volatile("" ::: "memory");                                            \
  }

#define VM10 asm volatile("s_waitcnt vmcnt(10)" ::: "memory")
#define VM8  asm volatile("s_waitcnt vmcnt(8)"  ::: "memory")
#define VM4  asm volatile("s_waitcnt vmcnt(4)"  ::: "memory")

template<int MODE>
__global__ __launch_bounds__(512, 2) void mgemm_kernel(
    const u16* __restrict__ A, const u16* __restrict__ Bt,
    const float* __restrict__ bias, const float* __restrict__ resid,
    float* __restrict__ Cf, u16* __restrict__ Cb, u16* __restrict__ Cb2)
{
  __shared__ __align__(16) u16 lds[65536];   // 64 KB A-ring + epilogue reuse

  const int tid = threadIdx.x, lane = tid & 63, wid = tid >> 6;
  const int wm = wid >> 2, wn = wid & 3;
  const int l15 = lane & 15, quad = lane >> 4;

  // XCD-aware mapping: XCD x owns 8 M-tiles (4 MB A-panel, L2-resident),
  // all XCDs sweep N-columns in lockstep (B panels L3-shared).
  const int b = (int)blockIdx.x;
  const int xcd = b & 7, ib = b >> 3;
  const int row0 = ((xcd << 3) + (ib & 7)) << 8;
  const int col0 = (ib >> 3) << 8;

  // A staging: pre-swizzled global source, lane-linear LDS dest.
  const int sc   = (tid & 7) ^ ((tid >> 3) & 7);
  const int srow = 2 * (tid >> 3) + (sc >> 2);
  const int skof = (sc & 3) << 3;
  const u16* Ag0 = A + (size_t)(row0 + srow) * K_ + skof;
  const u16* Ag1 = Ag0 + (size_t)128 * K_;

  // A fragment read offsets (paired-row + 3-bit XOR; consecutive-8-lane
  // batches of a ds_read_b128 cover all 8 bank groups)
  const int rhalf = l15 >> 1;
  const int cph   = ((((l15 & 1) << 2) | quad) ^ rhalf);
  const int aoffb = wm * 4096 + rhalf * 64 + cph * 8;

  // B fragment-major pointer: nb = col0/64 + wn
  const u16* Bp = Bt + (size_t)((col0 >> 6) + wn) * 65536 + lane * 8;

  f32x4 acc[8][4];
  #pragma unroll
  for (int i = 0; i < 8; ++i)
    #pragma unroll
    for (int j = 0; j < 4; ++j)
      acc[i][j] = (f32x4){0.f, 0.f, 0.f, 0.f};

  bf16x8 aA[4], aB[4], aT[4], bE[4], bO[4];

  // prologue: A slices 0..2 (6 loads) + B(0),B(1) (8 loads); VM10 confirms
  // slots 0 AND 1 staged (slice 0 phase B reads slot 1).
  #pragma unroll
  for (int t3 = 0; t3 < 3; ++t3) {
    u16* d_ = lds + t3 * 8192;
    gload16(Ag0 + t3 * 32, d_ + tid * 8);
    gload16(Ag1 + t3 * 32, d_ + 4096 + tid * 8);
  }
  BLOADS(bE, 0)
  BLOADS(bO, 1)
  asm volatile("s_waitcnt vmcnt(10)" ::: "memory");
  __builtin_amdgcn_s_barrier();
  __builtin_amdgcn_sched_barrier(0);
  asm volatile("" ::: "memory");

  // slice 0's row-half-0 regs
  aA[0] = *(const bf16x8*)(lds + aoffb);
  aA[1] = *(const bf16x8*)(lds + aoffb + 512);
  aA[2] = *(const bf16x8*)(lds + aoffb + 1024);
  aA[3] = *(const bf16x8*)(lds + aoffb + 1536);

  // main: 32 slices of K=32; stage A(s+3), load B(s+2).
  #pragma unroll 1
  for (int s = 0; s < 28; s += 2) {
    MSLICE2(s & 3, (s + 1) & 3, (s + 3) * 32, 1, 1, 1, s + 2, aA, aT, aB, bE, bE, VM10)
    MSLICE2((s + 1) & 3, (s + 2) & 3, (s + 4) * 32, 1, 1, 1, s + 3, aB, aT, aA, bO, bO, VM10)
  }
  MSLICE2(0, 1, 31 * 32, 1, 1, 1, 30, aA, aT, aB, bE, bE, VM10)   // s=28
  MSLICE2(1, 2, 0,       0, 1, 1, 31, aB, aT, aA, bO, bO, VM8 )   // s=29
  MSLICE2(2, 3, 0,       0, 1, 0, 0,  aA, aT, aB, bE, bE, VM4 )   // s=30
  MSLICE2(3, 0, 0,       0, 0, 0, 0,  aB, aT, aA, bO, bO, (void)0)// s=31

  if (MODE == 1 || MODE == 3) {
    // fp32 row-major epilogue (dword-coalesced scalar stores)
    const int rbase = row0 + wm * 128;
    #pragma unroll
    for (int j = 0; j < 4; ++j) {
      const int n = col0 + wn * 64 + j * 16 + l15;
      const float bn = bias[n];
      #pragma unroll
      for (int i = 0; i < 8; ++i)
        #pragma unroll
        for (int r = 0; r < 4; ++r) {
          const int row = rbase + i * 16 + quad * 4 + r;
          const size_t idx = (size_t)row * E_ + n;
          float v = acc[i][j][r] + bn;
          if (MODE == 1) Cf[idx] = v + resid[idx];
          else           Cf[idx] = v + Cf[idx];
        }
    }
    return;
  }

  // ---- bf16 epilogues via per-wave 16-KB LDS transpose -> 16-B coalesced stores ----
  u16* ep = lds + wid * 8192;                  // 128x64 u16, row stride 64
  const int nb0 = col0 + wn * 64;              // wave's 64-col window (64-aligned)

  if (MODE == 2) {
    #pragma unroll
    for (int j = 0; j < 4; ++j) {
      const float bn = bias[nb0 + j * 16 + l15];
      #pragma unroll
      for (int i = 0; i < 8; ++i)
        #pragma unroll
        for (int r = 0; r < 4; ++r)
          ep[(i*16 + quad*4 + r) * 64 + j*16 + l15] =
              f2bf(fmaxf(acc[i][j][r] + bn, 0.f));
    }
    __syncthreads();
    const int rbase = row0 + wm * 128;
    #pragma unroll
    for (int it = 0; it < 16; ++it) {
      const int tl = it * 8 + (lane >> 3), c = lane & 7;
      uint4 v = *(const uint4*)(ep + tl * 64 + c * 8);
      *(uint4*)(Cb + (size_t)(rbase + tl) * E_ + nb0 + c * 8) = v;
    }
    return;
  }

  // MODE 0: z = 0 (k), 1 (q): row-major (b,h,t,d). z = 2 (v): transposed (b,h,d,t).
  const int z = nb0 >> 10, hh = (nb0 >> 6) & 15;
  const int rows0 = row0 + wm * 128;
  const int bb = rows0 >> 8, tb0 = rows0 & 255;
  if (z < 2) {
    #pragma unroll
    for (int i = 0; i < 8; ++i)
      #pragma unroll
      for (int j = 0; j < 4; ++j)
        #pragma unroll
        for (int r = 0; r < 4; ++r)
          ep[(i*16 + quad*4 + r) * 64 + j*16 + l15] = f2bf(acc[i][j][r]);
    __syncthreads();
    u16* out = (z == 0 ? Cb : Cb2) + ((size_t)(bb * H_ + hh) * T_ + tb0) * HD_;
    #pragma unroll
    for (int it = 0; it < 16; ++it) {
      const int tl = it * 8 + (lane >> 3), c = lane & 7;
      uint4 v = *(const uint4*)(ep + tl * 64 + c * 8);
      *(uint4*)(out + (size_t)tl * HD_ + c * 8) = v;
    }
  } else {
    // write transposed [d][t'], 16B chunks swizzled: phys = (t'>>3) ^ (d&15)
    #pragma unroll
    for (int i = 0; i < 8; ++i)
      #pragma unroll
      for (int j = 0; j < 4; ++j)
        #pragma unroll
        for (int r = 0; r < 4; ++r) {
          const int tl = i*16 + quad*4 + r, d = j*16 + l15;
          const int phys = (tl >> 3) ^ (d & 15);
          ep[d * 128 + phys * 8 + (tl & 7)] = f2bf(acc[i][j][r]);
        }
    __syncthreads();
    u16* out = (u16*)Cf + ((size_t)(bb * H_ + hh) * HD_) * T_;
    #pragma unroll
    for (int it = 0; it < 16; ++it) {
      const int d = it * 4 + (lane >> 4), c = lane & 15;
      const int phys = c ^ (d & 15);
      uint4 v = *(const uint4*)(ep + d * 128 + phys * 8);
      *(uint4*)(out + (size_t)d * T_ + tb0 + c * 8) = v;
    }
  }
}

// ---------- MFMA flash attention: block = 4 bh's at one tblk ----------
// scores[t][s] = k_t . q_s / 8 (K.Q^T per reference), causal s<=t.
// k,q bf16 (b,h,t,d); vt bf16 (b,h,d,t); out bf16 row-major (b,t,h*64+d).
// Pb is per-wave PRIVATE: no __syncthreads anywhere -- wave-local LDS
// write->read ordering is compiler-inserted lgkmcnt; waves free-run.
__global__ __launch_bounds__(256) void fattn_kernel(
    const u16* __restrict__ kk_, const u16* __restrict__ qq_,
    const u16* __restrict__ vt_, u16* __restrict__ out)
{
  __shared__ __align__(16) u16 Pb[4][64 * 72];  // per-wave private, 9216 B each
  const int tid = threadIdx.x, lane = tid & 63, wv = tid >> 6;
  const int bh = blockIdx.x * 4 + wv;
  const int tblk = blockIdx.y;
  const int l15 = lane & 15, quad = lane >> 4;
  const u16* kb  = kk_ + (size_t)bh * (T_ * HD_);
  const u16* qb  = qq_ + (size_t)bh * (T_ * HD_);
  const u16* vtb = vt_ + (size_t)bh * (HD_ * T_);
  u16* Pw = Pb[wv];

  bf16x8 kf[4][2];
  #pragma unroll
  for (int i = 0; i < 4; ++i)
    #pragma unroll
    for (int c = 0; c < 2; ++c)
      kf[i][c] = *(const bf16x8*)(kb + (size_t)(tblk*64 + i*16 + l15) * HD_ + c*32 + quad*8);

  f32x4 o[4][4];
  float mrow[4][4], lrow[4][4];
  #pragma unroll
  for (int i = 0; i < 4; ++i) {
    #pragma unroll
    for (int j = 0; j < 4; ++j) o[i][j] = (f32x4){0.f, 0.f, 0.f, 0.f};
    #pragma unroll
    for (int r = 0; r < 4; ++r) { mrow[i][r] = -1e30f; lrow[i][r] = 0.f; }
  }

  for (int sb = 0; sb <= tblk; ++sb) {
    f32x4 S[4][4];
    #pragma unroll
    for (int j = 0; j < 4; ++j) {
      bf16x8 qf0 = *(const bf16x8*)(qb + (size_t)(sb*64 + j*16 + l15) * HD_ +      quad*8);
      bf16x8 qf1 = *(const bf16x8*)(qb + (size_t)(sb*64 + j*16 + l15) * HD_ + 32 + quad*8);
      #pragma unroll
      for (int i = 0; i < 4; ++i) {
        f32x4 t0 = __builtin_amdgcn_mfma_f32_16x16x32_bf16(kf[i][0], qf0,
                       (f32x4){0.f,0.f,0.f,0.f}, 0, 0, 0);
        S[i][j] = __builtin_amdgcn_mfma_f32_16x16x32_bf16(kf[i][1], qf1, t0, 0, 0, 0);
      }
    }
    #pragma unroll
    for (int i = 0; i < 4; ++i)
      #pragma unroll
      for (int j = 0; j < 4; ++j)
        #pragma unroll
        for (int r = 0; r < 4; ++r) {
          float val = S[i][j][r] * 0.125f;
          if (sb == tblk) {
            int tl = i*16 + quad*4 + r, sl = j*16 + l15;
            if (sl > tl) val = -1e30f;
          }
          S[i][j][r] = val;
        }
    #pragma unroll
    for (int i = 0; i < 4; ++i)
      #pragma unroll
      for (int r = 0; r < 4; ++r) {
        float mx = fmaxf(fmaxf(S[i][0][r], S[i][1][r]), fmaxf(S[i][2][r], S[i][3][r]));
        #pragma unroll
        for (int msk = 1; msk < 16; msk <<= 1) mx = fmaxf(mx, __shfl_xor(mx, msk));
        float mn = fmaxf(mrow[i][r], mx);
        float al = __expf(mrow[i][r] - mn);
        mrow[i][r] = mn;
        float sm = 0.f;
        #pragma unroll
        for (int j = 0; j < 4; ++j) {
          float p = __expf(S[i][j][r] - mn);
          S[i][j][r] = p;
          sm += p;
        }
        #pragma unroll
        for (int msk = 1; msk < 16; msk <<= 1) sm += __shfl_xor(sm, msk);
        lrow[i][r] = lrow[i][r] * al + sm;
        #pragma unroll
        for (int jd = 0; jd < 4; ++jd) o[i][jd][r] *= al;
      }
    #pragma unroll
    for (int i = 0; i < 4; ++i)
      #pragma unroll
      for (int j = 0; j < 4; ++j)
        #pragma unroll
        for (int r = 0; r < 4; ++r)
          Pw[(i*16 + quad*4 + r) * 72 + j*16 + l15] = f2bf_trunc(S[i][j][r]);
    bf16x8 pf[4][2];
    #pragma unroll
    for (int i = 0; i < 4; ++i)
      #pragma unroll
      for (int c = 0; c < 2; ++c)
        pf[i][c] = *(const bf16x8*)(Pw + (i*16 + l15) * 72 + c*32 + quad*8);
    #pragma unroll
    for (int jd = 0; jd < 4; ++jd) {
      bf16x8 vf0 = *(const bf16x8*)(vtb + (size_t)(jd*16 + l15) * T_ + sb*64 +      quad*8);
      bf16x8 vf1 = *(const bf16x8*)(vtb + (size_t)(jd*16 + l15) * T_ + sb*64 + 32 + quad*8);
      #pragma unroll
      for (int i = 0; i < 4; ++i) {
        f32x4 t0 = __builtin_amdgcn_mfma_f32_16x16x32_bf16(pf[i][0], vf0, o[i][jd], 0, 0, 0);
        o[i][jd] = __builtin_amdgcn_mfma_f32_16x16x32_bf16(pf[i][1], vf1, t0, 0, 0, 0);
      }
    }
  }

  #pragma unroll
  for (int i = 0; i < 4; ++i)
    #pragma unroll
    for (int r = 0; r < 4; ++r) {
      float inv = 1.0f / lrow[i][r];
      #pragma unroll
      for (int jd = 0; jd < 4; ++jd)
        Pw[(i*16 + quad*4 + r) * 72 + jd*16 + l15] = f2bf(o[i][jd][r] * inv);
    }
  {
    const int b = bh >> 4, h = bh & 15;
    const uint4* pr = (const uint4*)(Pw + lane * 72);
    uint4* og = (uint4*)(out + ((size_t)(b * T_ + tblk*64 + lane)) * E_ + h * HD_);
    #pragma unroll
    for (int k = 0; k < 8; ++k) og[k] = pr[k];
  }
}

// ---------- launch ----------
extern "C" void kernel_launch(void* const* d_in, const int* in_sizes, int n_in,
                              void* d_out, int out_size, void* d_ws, size_t ws_size,
                              hipStream_t stream) {
  const float* x     = (const float*)d_in[0];
  const float* ln1g  = (const float*)d_in[1];
  const float* ln1b  = (const float*)d_in[2];
  const float* wk    = (const float*)d_in[3];
  const float* wq    = (const float*)d_in[4];
  const float* wv    = (const float*)d_in[5];
  const float* wproj = (const float*)d_in[6];
  const float* bproj = (const float*)d_in[7];
  const float* ln2g  = (const float*)d_in[8];
  const float* ln2b  = (const float*)d_in[9];
  const float* w1    = (const float*)d_in[10];
  const float* b1    = (const float*)d_in[11];
  const float* w2    = (const float*)d_in[12];
  const float* b2    = (const float*)d_in[13];
  float* outp = (float*)d_out;

  // ws (112 MB <= proven 128 MB):
  //  [0,6M) WqkvF | [6,8M) WprojF | [8,10M) W1F | [10,12M) W2F   (fragment-major)
  //  [16,48M) hb bf16 (LN1 out -> attn out)
  //  [48,80M) k bf16 (bhtd) -> h2 bf16 | [80,112M) q bf16 (bhtd) -> ff1 bf16
  // d_out (64MB): v^T bf16 (b,h,d,t) [0,32M) -> x1 fp32 (full) -> out (in-place)
  char* ws = (char*)d_ws;
  const size_t MB = 1024 * 1024;
  u16* wqkvT  = (u16*)(ws);
  u16* wprojT = (u16*)(ws + 6 * MB);
  u16* w1T    = (u16*)(ws + 8 * MB);
  u16* w2T    = (u16*)(ws + 10 * MB);
  u16* hb     = (u16*)(ws + 16 * MB);
  u16* kbuf   = (u16*)(ws + 48 * MB);
  u16* qbuf   = (u16*)(ws + 80 * MB);
  u16* vtbuf  = (u16*)d_out;                   // v^T (b,h,d,t) bf16

  convq_kernel<<<dim3(48, 16), 256, 0, stream>>>(wk, wq, wv, wqkvT);
  convt_kernel<<<dim3(16, 16), 256, 0, stream>>>(wproj, wprojT);
  convt_kernel<<<dim3(16, 16), 256, 0, stream>>>(w1, w1T);
  convt_kernel<<<dim3(16, 16), 256, 0, stream>>>(w2, w2T);

  // 1) hb = LN1(x) bf16
  ln_bf16_kernel<<<NTOK/4, 256, 0, stream>>>(x, ln1g, ln1b, hb);
  // 2) k,q bf16 (bhtd) + v^T bf16 (bhdt, d_out) = hb @ WqkvF
  mgemm_kernel<0><<<768, 512, 0, stream>>>(
      hb, wqkvT, nullptr, nullptr, (float*)vtbuf, kbuf, qbuf);
  // 3) MFMA flash attention -> bf16 row-major into hb
  fattn_kernel<<<dim3(B_*H_/4, 4), 256, 0, stream>>>(kbuf, qbuf, vtbuf, hb);
  // 4) x1 = x + attn @ wproj + bproj -> fp32 d_out (v^T dead)
  mgemm_kernel<1><<<256, 512, 0, stream>>>(
      hb, wprojT, bproj, x, outp, nullptr, nullptr);
  // 5) h2 = LN2(x1) bf16 (over dead k)
  ln_bf16_kernel<<<NTOK/4, 256, 0, stream>>>(outp, ln2g, ln2b, kbuf);
  // 6) ff1 = relu(h2 @ w1 + b1) bf16 (over dead q)
  mgemm_kernel<2><<<256, 512, 0, stream>>>(
      kbuf, w1T, b1, nullptr, nullptr, qbuf, nullptr);
  // 7) out = x1 + ff1 @ w2 + b2, in-place over d_out
  mgemm_kernel<3><<<256, 512, 0, stream>>>(
      qbuf, w2T, b2, nullptr, outp, nullptr, nullptr);
}